// Round 1
// baseline (3694.965 us; speedup 1.0000x reference)
//
#include <hip/hip_runtime.h>
#include <hip/hip_bf16.h>

#define NNODES 10000
#define NEDGES 320000

// ---------------------------------------------------------------------------
// conv1: h[n,o,l] = sum_c x[n,c,l]*w1[o,c] + b1[o]   (x: N x 5 x 140, w1: 64x5)
// writes pre-BN result to outp (cnn1 region of d_out), accumulates per-channel
// sum/sumsq (over N*140) via block-partials + one atomic per channel per block.
// Thread mapping: o = tid>>2 (fixed per thread), lg = tid&3 owns float4 chunks
// j == lg (mod 4) of the 35 chunks per row.
// ---------------------------------------------------------------------------
__global__ __launch_bounds__(256) void conv1_stats(
    const float* __restrict__ x, const float* __restrict__ w1,
    const float* __restrict__ b1, float* __restrict__ outp,
    float* __restrict__ ssum, float* __restrict__ sssq) {
  __shared__ float4 xs4[5 * 36];   // rows padded to 36 float4 (pad zeroed)
  __shared__ float red[512];
  const int tid = threadIdx.x;
  const int o = tid >> 2, lg = tid & 3;
  float w[5];
#pragma unroll
  for (int c = 0; c < 5; ++c) w[c] = w1[o * 5 + c];
  const float bias = b1[o];
  float bsum = 0.f, bssq = 0.f;
  for (int n = blockIdx.x; n < NNODES; n += gridDim.x) {
    const float4* src = (const float4*)(x + (size_t)n * 700);
    for (int i = tid; i < 175; i += 256) {
      int r = i / 35, cdx = i - r * 35;
      xs4[r * 36 + cdx] = src[i];
    }
    if (tid < 5) xs4[tid * 36 + 35] = make_float4(0.f, 0.f, 0.f, 0.f);
    __syncthreads();
    float4* dst = (float4*)(outp + (size_t)n * 8960 + o * 140);
#pragma unroll
    for (int t = 0; t < 9; ++t) {
      int chunk = lg + 4 * t;
      float4 acc = make_float4(bias, bias, bias, bias);
#pragma unroll
      for (int c = 0; c < 5; ++c) {
        float wv = w[c];
        float4 xv = xs4[c * 36 + (chunk < 35 ? chunk : 35)];
        acc.x += wv * xv.x; acc.y += wv * xv.y;
        acc.z += wv * xv.z; acc.w += wv * xv.w;
      }
      if (chunk < 35) {
        dst[chunk] = acc;
        bsum += acc.x + acc.y + acc.z + acc.w;
        bssq += acc.x * acc.x + acc.y * acc.y + acc.z * acc.z + acc.w * acc.w;
      }
    }
    __syncthreads();
  }
  red[tid] = bsum; red[256 + tid] = bssq;
  __syncthreads();
  if (tid < 64) {
    float s = 0.f, q = 0.f;
#pragma unroll
    for (int g = 0; g < 4; ++g) { s += red[tid * 4 + g]; q += red[256 + tid * 4 + g]; }
    atomicAdd(&ssum[tid], s);
    atomicAdd(&sssq[tid], q);
  }
}

// ---------------------------------------------------------------------------
// conv2: x2[n,o,l] = sum_c h[n,c,l]*w2[o,c] + b2[o]  (h: N x 64 x 140 = cnn1)
// w2 staged transposed in LDS (ws2[c*64+o]) so per-c reads are conflict-free.
// ---------------------------------------------------------------------------
__global__ __launch_bounds__(256) void conv2_stats(
    const float* __restrict__ hin, const float* __restrict__ w2,
    const float* __restrict__ b2, float* __restrict__ outp,
    float* __restrict__ ssum, float* __restrict__ sssq) {
  __shared__ float4 xs4[64 * 36];   // 36 KB
  __shared__ float ws2[64 * 64];    // 16 KB, transposed
  __shared__ float red[512];
  const int tid = threadIdx.x;
  const int o = tid >> 2, lg = tid & 3;
  for (int i = tid; i < 4096; i += 256) {
    int oo = i >> 6, cc = i & 63;
    ws2[cc * 64 + oo] = w2[i];
  }
  const float bias = b2[o];
  float bsum = 0.f, bssq = 0.f;
  for (int n = blockIdx.x; n < NNODES; n += gridDim.x) {
    const float4* src = (const float4*)(hin + (size_t)n * 8960);
    for (int i = tid; i < 2240; i += 256) {
      int r = i / 35, cdx = i - r * 35;
      xs4[r * 36 + cdx] = src[i];
    }
    for (int i = tid; i < 64; i += 256) xs4[i * 36 + 35] = make_float4(0.f, 0.f, 0.f, 0.f);
    __syncthreads();
    float4 acc[9];
#pragma unroll
    for (int t = 0; t < 9; ++t) acc[t] = make_float4(bias, bias, bias, bias);
    for (int c = 0; c < 64; ++c) {
      float wv = ws2[c * 64 + o];
#pragma unroll
      for (int t = 0; t < 9; ++t) {
        int chunk = lg + 4 * t;           // chunk==35 hits zeroed pad (harmless)
        float4 xv = xs4[c * 36 + (chunk < 35 ? chunk : 35)];
        acc[t].x += wv * xv.x; acc[t].y += wv * xv.y;
        acc[t].z += wv * xv.z; acc[t].w += wv * xv.w;
      }
    }
    float4* dst = (float4*)(outp + (size_t)n * 8960 + o * 140);
#pragma unroll
    for (int t = 0; t < 9; ++t) {
      int chunk = lg + 4 * t;
      if (chunk < 35) {
        float4 a = acc[t];
        dst[chunk] = a;
        bsum += a.x + a.y + a.z + a.w;
        bssq += a.x * a.x + a.y * a.y + a.z * a.z + a.w * a.w;
      }
    }
    __syncthreads();
  }
  red[tid] = bsum; red[256 + tid] = bssq;
  __syncthreads();
  if (tid < 64) {
    float s = 0.f, q = 0.f;
#pragma unroll
    for (int g = 0; g < 4; ++g) { s += red[tid * 4 + g]; q += red[256 + tid * 4 + g]; }
    atomicAdd(&ssum[tid], s);
    atomicAdd(&sssq[tid], q);
  }
}

// finalize channel/feature stats -> scale/shift  (x_bn = x*scale + shift)
__global__ void finalize_stats(const float* __restrict__ ssum, const float* __restrict__ sssq,
                               const float* __restrict__ g, const float* __restrict__ b,
                               float* __restrict__ scale, float* __restrict__ shift,
                               float invcnt, int F) {
  int f = blockIdx.x * blockDim.x + threadIdx.x;
  if (f >= F) return;
  float m = ssum[f] * invcnt;
  float var = sssq[f] * invcnt - m * m;
  float rs = rsqrtf(var + 1e-5f);
  float sc = g[f] * rs;
  scale[f] = sc;
  shift[f] = b[f] - m * sc;
}

// elementwise: io = relu(io*scale[o]+shift[o]) [+ resid]  over N x 64 x 140
__global__ __launch_bounds__(256) void bn_relu_chan(
    float* __restrict__ io, const float* __restrict__ resid,
    const float* __restrict__ scale, const float* __restrict__ shift, int total4) {
  int stride = gridDim.x * 256;
  float4* p = (float4*)io;
  const float4* r4 = (const float4*)resid;
  for (int i = blockIdx.x * 256 + threadIdx.x; i < total4; i += stride) {
    int o = (i / 35) & 63;
    float sc = scale[o], sh = shift[o];
    float4 v = p[i];
    v.x = fmaxf(v.x * sc + sh, 0.f);
    v.y = fmaxf(v.y * sc + sh, 0.f);
    v.z = fmaxf(v.z * sc + sh, 0.f);
    v.w = fmaxf(v.w * sc + sh, 0.f);
    if (resid) {
      float4 r = r4[i];
      v.x += r.x; v.y += r.y; v.z += r.z; v.w += r.w;
    }
    p[i] = v;
  }
}

// column stats over X (M x F), F in {64,256} (power of two)
__global__ __launch_bounds__(256) void col_stats(
    const float* __restrict__ X, int M, int F,
    float* __restrict__ ssum, float* __restrict__ sssq) {
  __shared__ float rs[256], rq[256];
  int tid = threadIdx.x;
  int rowsPer = 256 / F;
  int f = tid & (F - 1);
  int r0 = tid / F;
  float s = 0.f, q = 0.f;
  for (int n = blockIdx.x * rowsPer + r0; n < M; n += gridDim.x * rowsPer) {
    float v = X[(size_t)n * F + f];
    s += v; q += v * v;
  }
  if (rowsPer == 1) {
    atomicAdd(&ssum[f], s);
    atomicAdd(&sssq[f], q);
  } else {
    rs[tid] = s; rq[tid] = q;
    __syncthreads();
    if (tid < F) {
      float S = 0.f, Q = 0.f;
      for (int r = 0; r < rowsPer; ++r) { S += rs[r * F + tid]; Q += rq[r * F + tid]; }
      atomicAdd(&ssum[tid], S);
      atomicAdd(&sssq[tid], Q);
    }
  }
}

// hb = relu(h2*scale+shift [+ hb]); optional extra copy to finout
__global__ __launch_bounds__(256) void bn_relu_nodes(
    const float* __restrict__ h2, float* __restrict__ hb,
    const float* __restrict__ scale, const float* __restrict__ shift,
    float* __restrict__ finout, int do_res, int total4, int f4mask) {
  int stride = gridDim.x * 256;
  const float4* s4 = (const float4*)scale;
  const float4* sh4 = (const float4*)shift;
  for (int i = blockIdx.x * 256 + threadIdx.x; i < total4; i += stride) {
    int f4 = i & f4mask;
    float4 sc = s4[f4], sh = sh4[f4];
    float4 v = ((const float4*)h2)[i];
    v.x = v.x * sc.x + sh.x; v.y = v.y * sc.y + sh.y;
    v.z = v.z * sc.z + sh.z; v.w = v.w * sc.w + sh.w;
    if (do_res) {
      float4 pr = ((const float4*)hb)[i];
      v.x += pr.x; v.y += pr.y; v.z += pr.z; v.w += pr.w;
    }
    v.x = fmaxf(v.x, 0.f); v.y = fmaxf(v.y, 0.f);
    v.z = fmaxf(v.z, 0.f); v.w = fmaxf(v.w, 0.f);
    ((float4*)hb)[i] = v;
    if (finout) ((float4*)finout)[i] = v;
  }
}

// ---------------------------------------------------------------------------
// graph prep: degree histogram, exclusive scan -> rowstart, CSR fill
// ---------------------------------------------------------------------------
__global__ void hist_deg(const int* __restrict__ e, int* __restrict__ deg) {
  for (int i = blockIdx.x * blockDim.x + threadIdx.x; i < NEDGES;
       i += gridDim.x * blockDim.x)
    atomicAdd(&deg[e[2 * i + 1]], 1);
}

__global__ __launch_bounds__(1024) void scan_deg(const int* __restrict__ deg,
                                                 int* __restrict__ rowstart,
                                                 float* __restrict__ denom) {
  __shared__ int buf[1024];
  __shared__ int carry_s;
  int tid = threadIdx.x;
  if (tid == 0) carry_s = 0;
  __syncthreads();
  for (int base = 0; base < NNODES; base += 1024) {
    int idx = base + tid;
    int v = (idx < NNODES) ? deg[idx] : 0;
    buf[tid] = v;
    __syncthreads();
    for (int off = 1; off < 1024; off <<= 1) {
      int t = (tid >= off) ? buf[tid - off] : 0;
      __syncthreads();
      buf[tid] += t;
      __syncthreads();
    }
    int incl = buf[tid];
    int tot = buf[1023];
    int c = carry_s;
    __syncthreads();
    if (idx < NNODES) {
      rowstart[idx] = c + incl - v;
      denom[idx] = (v > 1) ? (float)v : 1.0f;
    }
    if (tid == 0) carry_s = c + tot;
    __syncthreads();
  }
  if (tid == 0) rowstart[NNODES] = carry_s;
}

__global__ void fill_csr(const int* __restrict__ e, const int* __restrict__ rowstart,
                         int* __restrict__ cursor, int* __restrict__ csr) {
  for (int i = blockIdx.x * blockDim.x + threadIdx.x; i < NEDGES;
       i += gridDim.x * blockDim.x) {
    int s = e[2 * i], d = e[2 * i + 1];
    int pos = rowstart[d] + atomicAdd(&cursor[d], 1);
    csr[pos] = s;
  }
}

// h2[n,:] = hs[n,:] + (sum_{s in in(n)} hn[s,:]) / denom[n] + bb[:]
// one 64-lane wave per node, lane owns a float4 of the 256 features.
__global__ __launch_bounds__(256) void combine_neigh(
    const float* __restrict__ hs, const float* __restrict__ hn,
    const int* __restrict__ rowstart, const int* __restrict__ csr,
    const float* __restrict__ denom, const float* __restrict__ bb,
    float* __restrict__ h2) {
  int wid = threadIdx.x >> 6, lane = threadIdx.x & 63;
  int n = blockIdx.x * 4 + wid;
  if (n >= NNODES) return;
  int p0 = rowstart[n], p1 = rowstart[n + 1];
  float4 acc = make_float4(0.f, 0.f, 0.f, 0.f);
  for (int p = p0; p < p1; ++p) {
    int s = csr[p];
    float4 v = *(const float4*)(hn + (size_t)s * 256 + lane * 4);
    acc.x += v.x; acc.y += v.y; acc.z += v.z; acc.w += v.w;
  }
  float inv = 1.0f / denom[n];
  float4 hv = *(const float4*)(hs + (size_t)n * 256 + lane * 4);
  float4 bv = *(const float4*)(bb + lane * 4);
  float4 o;
  o.x = hv.x + acc.x * inv + bv.x;
  o.y = hv.y + acc.y * inv + bv.y;
  o.z = hv.z + acc.z * inv + bv.z;
  o.w = hv.w + acc.w * inv + bv.w;
  *(float4*)(h2 + (size_t)n * 256 + lane * 4) = o;
}

// ---------------------------------------------------------------------------
// fp32 SIMT GEMM: C = A(MxK) @ B(KxNcols), optionally two B/C pairs sharing A.
// BM=128, BN=64, BK=16, 256 threads, 8x4 microtile, A transposed in LDS.
// ---------------------------------------------------------------------------
__global__ __launch_bounds__(256) void gemm_dual(
    const float* __restrict__ A, const float* __restrict__ B0,
    const float* __restrict__ B1, float* __restrict__ C0,
    float* __restrict__ C1, int M, int K, int ncols) {
  __shared__ float Ast[16][128];
  __shared__ float Bs[16][64];
  const int tid = threadIdx.x;
  int cb = blockIdx.x;
  const int per = ncols >> 6;
  const float* B = B0;
  float* C = C0;
  if (cb >= per) { B = B1; C = C1; cb -= per; }
  const int bn = cb << 6;
  const int bm = blockIdx.y << 7;
  const int ty = tid >> 4, tx = tid & 15;
  float acc[8][4] = {};
  for (int k0 = 0; k0 < K; k0 += 16) {
#pragma unroll
    for (int i = 0; i < 2; ++i) {
      int idx = tid + i * 256;
      int r = idx >> 2, kq = (idx & 3) << 2;
      float4 v = make_float4(0.f, 0.f, 0.f, 0.f);
      int row = bm + r;
      if (row < M) v = *(const float4*)(A + (size_t)row * K + k0 + kq);
      Ast[kq + 0][r] = v.x; Ast[kq + 1][r] = v.y;
      Ast[kq + 2][r] = v.z; Ast[kq + 3][r] = v.w;
    }
    {
      int kb = tid >> 4, nq = (tid & 15) << 2;
      *(float4*)&Bs[kb][nq] = *(const float4*)(B + (size_t)(k0 + kb) * ncols + bn + nq);
    }
    __syncthreads();
#pragma unroll
    for (int kk = 0; kk < 16; ++kk) {
      float4 a0 = *(const float4*)&Ast[kk][ty * 8];
      float4 a1 = *(const float4*)&Ast[kk][ty * 8 + 4];
      float4 b = *(const float4*)&Bs[kk][tx * 4];
      float av[8] = {a0.x, a0.y, a0.z, a0.w, a1.x, a1.y, a1.z, a1.w};
      float bv[4] = {b.x, b.y, b.z, b.w};
#pragma unroll
      for (int i2 = 0; i2 < 8; ++i2)
#pragma unroll
        for (int j2 = 0; j2 < 4; ++j2) acc[i2][j2] += av[i2] * bv[j2];
    }
    __syncthreads();
  }
#pragma unroll
  for (int i2 = 0; i2 < 8; ++i2) {
    int row = bm + ty * 8 + i2;
    if (row < M) {
      float4 v = make_float4(acc[i2][0], acc[i2][1], acc[i2][2], acc[i2][3]);
      *(float4*)(C + (size_t)row * ncols + bn + tx * 4) = v;
    }
  }
}

// final tiny GEMM: out[n,k] = sum_j a[n,j]*w2[j,k] + b2[k], k in {0,1}
__global__ __launch_bounds__(256) void mlp_out(
    const float* __restrict__ a, const float* __restrict__ w2,
    const float* __restrict__ b2, float* __restrict__ out) {
  __shared__ float ws[128];
  __shared__ float bs[2];
  int tid = threadIdx.x;
  if (tid < 128) ws[tid] = w2[tid];
  if (tid < 2) bs[tid] = b2[tid];
  __syncthreads();
  int n = blockIdx.x * 256 + tid;
  if (n >= NNODES) return;
  const float* ar = a + (size_t)n * 64;
  float a0 = bs[0], a1 = bs[1];
#pragma unroll 8
  for (int j = 0; j < 64; ++j) {
    float v = ar[j];
    a0 += v * ws[2 * j];
    a1 += v * ws[2 * j + 1];
  }
  out[2 * n] = a0;
  out[2 * n + 1] = a1;
}

// ---------------------------------------------------------------------------
extern "C" void kernel_launch(void* const* d_in, const int* in_sizes, int n_in,
                              void* d_out, int out_size, void* d_ws, size_t ws_size,
                              hipStream_t stream) {
  const float* x       = (const float*)d_in[0];
  const float* conv1_w = (const float*)d_in[1];
  const float* conv1_b = (const float*)d_in[2];
  const float* bn_c1_g = (const float*)d_in[3];
  const float* bn_c1_b = (const float*)d_in[4];
  const float* conv2_w = (const float*)d_in[5];
  const float* conv2_b = (const float*)d_in[6];
  const float* bn_c2_g = (const float*)d_in[7];
  const float* bn_c2_b = (const float*)d_in[8];
  const float* ws0     = (const float*)d_in[9];
  const float* wn0     = (const float*)d_in[10];
  const float* b0      = (const float*)d_in[11];
  const float* ws_rest = (const float*)d_in[12];
  const float* wn_rest = (const float*)d_in[13];
  const float* b_rest  = (const float*)d_in[14];
  const float* bn_g    = (const float*)d_in[15];
  const float* bn_b    = (const float*)d_in[16];
  const float* mlp_w1  = (const float*)d_in[17];
  const float* mlp_b1  = (const float*)d_in[18];
  const float* mlp_bn_g= (const float*)d_in[19];
  const float* mlp_bn_b= (const float*)d_in[20];
  const float* mlp_w2  = (const float*)d_in[21];
  const float* mlp_b2  = (const float*)d_in[22];
  const int*   edges   = (const int*)d_in[23];

  float* outp = (float*)d_out;
  float* cnn1 = outp + 20000;
  float* cnn2 = cnn1 + (size_t)NNODES * 8960;
  float* fin  = cnn2 + (size_t)NNODES * 8960;

  float* F    = (float*)d_ws;
  float* ssum  = F;                 // 256
  float* sssq  = F + 256;           // 256
  float* scale = F + 512;           // 256
  float* shift = F + 768;           // 256
  float* denom = F + 1024;          // N
  float* hbuf  = F + 11024;         // N*256
  float* hs    = hbuf + (size_t)NNODES * 256;
  float* hn    = hs + (size_t)NNODES * 256;
  float* h2    = hn + (size_t)NNODES * 256;
  float* a64   = h2 + (size_t)NNODES * 256;   // N*64
  int* deg_i   = (int*)(a64 + (size_t)NNODES * 64);
  int* cursor  = deg_i + NNODES;
  int* rowstart= cursor + NNODES;   // N+1
  int* csr_src = rowstart + NNODES + 1;  // E

  // ---- CNN stage 1 ----
  hipMemsetAsync(ssum, 0, 512 * sizeof(float), stream);
  conv1_stats<<<512, 256, 0, stream>>>(x, conv1_w, conv1_b, cnn1, ssum, sssq);
  finalize_stats<<<1, 64, 0, stream>>>(ssum, sssq, bn_c1_g, bn_c1_b, scale, shift,
                                       1.f / 1400000.f, 64);
  bn_relu_chan<<<2048, 256, 0, stream>>>(cnn1, nullptr, scale, shift, 22400000);

  // ---- CNN stage 2 (+residual) ----
  hipMemsetAsync(ssum, 0, 512 * sizeof(float), stream);
  conv2_stats<<<1024, 256, 0, stream>>>(cnn1, conv2_w, conv2_b, cnn2, ssum, sssq);
  finalize_stats<<<1, 64, 0, stream>>>(ssum, sssq, bn_c2_g, bn_c2_b, scale, shift,
                                       1.f / 1400000.f, 64);
  bn_relu_chan<<<2048, 256, 0, stream>>>(cnn2, cnn1, scale, shift, 22400000);

  // ---- graph prep (CSR) ----
  hipMemsetAsync(deg_i, 0, 2 * NNODES * sizeof(int), stream);  // deg + cursor
  hist_deg<<<512, 256, 0, stream>>>(edges, deg_i);
  scan_deg<<<1, 1024, 0, stream>>>(deg_i, rowstart, denom);
  fill_csr<<<512, 256, 0, stream>>>(edges, rowstart, cursor, csr_src);

  // ---- 4 SAGE layers ----
  for (int l = 0; l < 4; ++l) {
    const float* A   = (l == 0) ? cnn2 : hbuf;
    int K            = (l == 0) ? 8960 : 256;
    const float* Bws = (l == 0) ? ws0 : ws_rest + (size_t)(l - 1) * 65536;
    const float* Bwn = (l == 0) ? wn0 : wn_rest + (size_t)(l - 1) * 65536;
    const float* bb  = (l == 0) ? b0 : b_rest + (size_t)(l - 1) * 256;
    gemm_dual<<<dim3(8, 79), 256, 0, stream>>>(A, Bws, Bwn, hs, hn, NNODES, K, 256);
    combine_neigh<<<2500, 256, 0, stream>>>(hs, hn, rowstart, csr_src, denom, bb, h2);
    hipMemsetAsync(ssum, 0, 512 * sizeof(float), stream);
    col_stats<<<512, 256, 0, stream>>>(h2, NNODES, 256, ssum, sssq);
    finalize_stats<<<1, 256, 0, stream>>>(ssum, sssq, bn_g + l * 256, bn_b + l * 256,
                                          scale, shift, 1e-4f, 256);
    bn_relu_nodes<<<1024, 256, 0, stream>>>(h2, hbuf, scale, shift,
                                            (l == 3) ? fin : nullptr,
                                            (l > 0) ? 1 : 0, 640000, 63);
  }

  // ---- MLP head ----
  gemm_dual<<<dim3(1, 79), 256, 0, stream>>>(hbuf, mlp_w1, nullptr, a64, nullptr,
                                             NNODES, 256, 64);
  hipMemsetAsync(ssum, 0, 512 * sizeof(float), stream);
  col_stats<<<512, 256, 0, stream>>>(a64, NNODES, 64, ssum, sssq);
  finalize_stats<<<1, 64, 0, stream>>>(ssum, sssq, mlp_bn_g, mlp_bn_b, scale, shift,
                                       1e-4f, 64);
  bn_relu_nodes<<<512, 256, 0, stream>>>(a64, a64, scale, shift, nullptr, 0, 160000, 15);
  mlp_out<<<40, 256, 0, stream>>>(a64, mlp_w2, mlp_b2, outp);
}

// Round 2
// 2510.664 us; speedup vs baseline: 1.4717x; 1.4717x over previous
//
#include <hip/hip_runtime.h>
#include <hip/hip_bf16.h>

#define NNODES 10000
#define NEDGES 320000

typedef __attribute__((ext_vector_type(8))) short short8;
typedef __attribute__((ext_vector_type(4))) float f32x4;

// ---------------------------------------------------------------------------
// conv1: h[n,o,l] = sum_c x[n,c,l]*w1[o,c] + b1[o]   (x: N x 5 x 140, w1: 64x5)
// ---------------------------------------------------------------------------
__global__ __launch_bounds__(256) void conv1_stats(
    const float* __restrict__ x, const float* __restrict__ w1,
    const float* __restrict__ b1, float* __restrict__ outp,
    float* __restrict__ ssum, float* __restrict__ sssq) {
  __shared__ float4 xs4[5 * 36];
  __shared__ float red[512];
  const int tid = threadIdx.x;
  const int o = tid >> 2, lg = tid & 3;
  float w[5];
#pragma unroll
  for (int c = 0; c < 5; ++c) w[c] = w1[o * 5 + c];
  const float bias = b1[o];
  float bsum = 0.f, bssq = 0.f;
  for (int n = blockIdx.x; n < NNODES; n += gridDim.x) {
    const float4* src = (const float4*)(x + (size_t)n * 700);
    for (int i = tid; i < 175; i += 256) {
      int r = i / 35, cdx = i - r * 35;
      xs4[r * 36 + cdx] = src[i];
    }
    if (tid < 5) xs4[tid * 36 + 35] = make_float4(0.f, 0.f, 0.f, 0.f);
    __syncthreads();
    float4* dst = (float4*)(outp + (size_t)n * 8960 + o * 140);
#pragma unroll
    for (int t = 0; t < 9; ++t) {
      int chunk = lg + 4 * t;
      float4 acc = make_float4(bias, bias, bias, bias);
#pragma unroll
      for (int c = 0; c < 5; ++c) {
        float wv = w[c];
        float4 xv = xs4[c * 36 + (chunk < 35 ? chunk : 35)];
        acc.x += wv * xv.x; acc.y += wv * xv.y;
        acc.z += wv * xv.z; acc.w += wv * xv.w;
      }
      if (chunk < 35) {
        dst[chunk] = acc;
        bsum += acc.x + acc.y + acc.z + acc.w;
        bssq += acc.x * acc.x + acc.y * acc.y + acc.z * acc.z + acc.w * acc.w;
      }
    }
    __syncthreads();
  }
  red[tid] = bsum; red[256 + tid] = bssq;
  __syncthreads();
  if (tid < 64) {
    float s = 0.f, q = 0.f;
#pragma unroll
    for (int g = 0; g < 4; ++g) { s += red[tid * 4 + g]; q += red[256 + tid * 4 + g]; }
    atomicAdd(&ssum[tid], s);
    atomicAdd(&sssq[tid], q);
  }
}

// ---------------------------------------------------------------------------
// conv2: x2[n,o,l] = sum_c h[n,c,l]*w2[o,c] + b2[o]
// ---------------------------------------------------------------------------
__global__ __launch_bounds__(256) void conv2_stats(
    const float* __restrict__ hin, const float* __restrict__ w2,
    const float* __restrict__ b2, float* __restrict__ outp,
    float* __restrict__ ssum, float* __restrict__ sssq) {
  __shared__ float4 xs4[64 * 36];
  __shared__ float ws2[64 * 64];
  __shared__ float red[512];
  const int tid = threadIdx.x;
  const int o = tid >> 2, lg = tid & 3;
  for (int i = tid; i < 4096; i += 256) {
    int oo = i >> 6, cc = i & 63;
    ws2[cc * 64 + oo] = w2[i];
  }
  const float bias = b2[o];
  float bsum = 0.f, bssq = 0.f;
  for (int n = blockIdx.x; n < NNODES; n += gridDim.x) {
    const float4* src = (const float4*)(hin + (size_t)n * 8960);
    for (int i = tid; i < 2240; i += 256) {
      int r = i / 35, cdx = i - r * 35;
      xs4[r * 36 + cdx] = src[i];
    }
    for (int i = tid; i < 64; i += 256) xs4[i * 36 + 35] = make_float4(0.f, 0.f, 0.f, 0.f);
    __syncthreads();
    float4 acc[9];
#pragma unroll
    for (int t = 0; t < 9; ++t) acc[t] = make_float4(bias, bias, bias, bias);
    for (int c = 0; c < 64; ++c) {
      float wv = ws2[c * 64 + o];
#pragma unroll
      for (int t = 0; t < 9; ++t) {
        int chunk = lg + 4 * t;
        float4 xv = xs4[c * 36 + (chunk < 35 ? chunk : 35)];
        acc[t].x += wv * xv.x; acc[t].y += wv * xv.y;
        acc[t].z += wv * xv.z; acc[t].w += wv * xv.w;
      }
    }
    float4* dst = (float4*)(outp + (size_t)n * 8960 + o * 140);
#pragma unroll
    for (int t = 0; t < 9; ++t) {
      int chunk = lg + 4 * t;
      if (chunk < 35) {
        float4 a = acc[t];
        dst[chunk] = a;
        bsum += a.x + a.y + a.z + a.w;
        bssq += a.x * a.x + a.y * a.y + a.z * a.z + a.w * a.w;
      }
    }
    __syncthreads();
  }
  red[tid] = bsum; red[256 + tid] = bssq;
  __syncthreads();
  if (tid < 64) {
    float s = 0.f, q = 0.f;
#pragma unroll
    for (int g = 0; g < 4; ++g) { s += red[tid * 4 + g]; q += red[256 + tid * 4 + g]; }
    atomicAdd(&ssum[tid], s);
    atomicAdd(&sssq[tid], q);
  }
}

__global__ void finalize_stats(const float* __restrict__ ssum, const float* __restrict__ sssq,
                               const float* __restrict__ g, const float* __restrict__ b,
                               float* __restrict__ scale, float* __restrict__ shift,
                               float invcnt, int F) {
  int f = blockIdx.x * blockDim.x + threadIdx.x;
  if (f >= F) return;
  float m = ssum[f] * invcnt;
  float var = sssq[f] * invcnt - m * m;
  float rs = rsqrtf(var + 1e-5f);
  float sc = g[f] * rs;
  scale[f] = sc;
  shift[f] = b[f] - m * sc;
}

__global__ __launch_bounds__(256) void bn_relu_chan(
    float* __restrict__ io, const float* __restrict__ resid,
    const float* __restrict__ scale, const float* __restrict__ shift, int total4) {
  int stride = gridDim.x * 256;
  float4* p = (float4*)io;
  const float4* r4 = (const float4*)resid;
  for (int i = blockIdx.x * 256 + threadIdx.x; i < total4; i += stride) {
    int o = (i / 35) & 63;
    float sc = scale[o], sh = shift[o];
    float4 v = p[i];
    v.x = fmaxf(v.x * sc + sh, 0.f);
    v.y = fmaxf(v.y * sc + sh, 0.f);
    v.z = fmaxf(v.z * sc + sh, 0.f);
    v.w = fmaxf(v.w * sc + sh, 0.f);
    if (resid) {
      float4 r = r4[i];
      v.x += r.x; v.y += r.y; v.z += r.z; v.w += r.w;
    }
    p[i] = v;
  }
}

__global__ __launch_bounds__(256) void col_stats(
    const float* __restrict__ X, int M, int F,
    float* __restrict__ ssum, float* __restrict__ sssq) {
  __shared__ float rs[256], rq[256];
  int tid = threadIdx.x;
  int rowsPer = 256 / F;
  int f = tid & (F - 1);
  int r0 = tid / F;
  float s = 0.f, q = 0.f;
  for (int n = blockIdx.x * rowsPer + r0; n < M; n += gridDim.x * rowsPer) {
    float v = X[(size_t)n * F + f];
    s += v; q += v * v;
  }
  if (rowsPer == 1) {
    atomicAdd(&ssum[f], s);
    atomicAdd(&sssq[f], q);
  } else {
    rs[tid] = s; rq[tid] = q;
    __syncthreads();
    if (tid < F) {
      float S = 0.f, Q = 0.f;
      for (int r = 0; r < rowsPer; ++r) { S += rs[r * F + tid]; Q += rq[r * F + tid]; }
      atomicAdd(&ssum[tid], S);
      atomicAdd(&sssq[tid], Q);
    }
  }
}

__global__ __launch_bounds__(256) void bn_relu_nodes(
    const float* __restrict__ h2, float* __restrict__ hb,
    const float* __restrict__ scale, const float* __restrict__ shift,
    float* __restrict__ finout, int do_res, int total4, int f4mask) {
  int stride = gridDim.x * 256;
  const float4* s4 = (const float4*)scale;
  const float4* sh4 = (const float4*)shift;
  for (int i = blockIdx.x * 256 + threadIdx.x; i < total4; i += stride) {
    int f4 = i & f4mask;
    float4 sc = s4[f4], sh = sh4[f4];
    float4 v = ((const float4*)h2)[i];
    v.x = v.x * sc.x + sh.x; v.y = v.y * sc.y + sh.y;
    v.z = v.z * sc.z + sh.z; v.w = v.w * sc.w + sh.w;
    if (do_res) {
      float4 pr = ((const float4*)hb)[i];
      v.x += pr.x; v.y += pr.y; v.z += pr.z; v.w += pr.w;
    }
    v.x = fmaxf(v.x, 0.f); v.y = fmaxf(v.y, 0.f);
    v.z = fmaxf(v.z, 0.f); v.w = fmaxf(v.w, 0.f);
    ((float4*)hb)[i] = v;
    if (finout) ((float4*)finout)[i] = v;
  }
}

// ---------------------------------------------------------------------------
// graph prep
// ---------------------------------------------------------------------------
__global__ void hist_deg(const int* __restrict__ e, int* __restrict__ deg) {
  for (int i = blockIdx.x * blockDim.x + threadIdx.x; i < NEDGES;
       i += gridDim.x * blockDim.x)
    atomicAdd(&deg[e[2 * i + 1]], 1);
}

__global__ __launch_bounds__(1024) void scan_deg(const int* __restrict__ deg,
                                                 int* __restrict__ rowstart,
                                                 float* __restrict__ denom) {
  __shared__ int buf[1024];
  __shared__ int carry_s;
  int tid = threadIdx.x;
  if (tid == 0) carry_s = 0;
  __syncthreads();
  for (int base = 0; base < NNODES; base += 1024) {
    int idx = base + tid;
    int v = (idx < NNODES) ? deg[idx] : 0;
    buf[tid] = v;
    __syncthreads();
    for (int off = 1; off < 1024; off <<= 1) {
      int t = (tid >= off) ? buf[tid - off] : 0;
      __syncthreads();
      buf[tid] += t;
      __syncthreads();
    }
    int incl = buf[tid];
    int tot = buf[1023];
    int c = carry_s;
    __syncthreads();
    if (idx < NNODES) {
      rowstart[idx] = c + incl - v;
      denom[idx] = (v > 1) ? (float)v : 1.0f;
    }
    if (tid == 0) carry_s = c + tot;
    __syncthreads();
  }
  if (tid == 0) rowstart[NNODES] = carry_s;
}

__global__ void fill_csr(const int* __restrict__ e, const int* __restrict__ rowstart,
                         int* __restrict__ cursor, int* __restrict__ csr) {
  for (int i = blockIdx.x * blockDim.x + threadIdx.x; i < NEDGES;
       i += gridDim.x * blockDim.x) {
    int s = e[2 * i], d = e[2 * i + 1];
    int pos = rowstart[d] + atomicAdd(&cursor[d], 1);
    csr[pos] = s;
  }
}

// h2[n,:] = hsn[n,0:256] + (sum_{s in in(n)} hsn[s,256:512]) / denom[n] + bb
__global__ __launch_bounds__(256) void combine_neigh(
    const float* __restrict__ hsn,
    const int* __restrict__ rowstart, const int* __restrict__ csr,
    const float* __restrict__ denom, const float* __restrict__ bb,
    float* __restrict__ h2) {
  int wid = threadIdx.x >> 6, lane = threadIdx.x & 63;
  int n = blockIdx.x * 4 + wid;
  if (n >= NNODES) return;
  int p0 = rowstart[n], p1 = rowstart[n + 1];
  float4 acc = make_float4(0.f, 0.f, 0.f, 0.f);
  for (int p = p0; p < p1; ++p) {
    int s = csr[p];
    float4 v = *(const float4*)(hsn + (size_t)s * 512 + 256 + lane * 4);
    acc.x += v.x; acc.y += v.y; acc.z += v.z; acc.w += v.w;
  }
  float inv = 1.0f / denom[n];
  float4 hv = *(const float4*)(hsn + (size_t)n * 512 + lane * 4);
  float4 bv = *(const float4*)(bb + lane * 4);
  float4 o;
  o.x = hv.x + acc.x * inv + bv.x;
  o.y = hv.y + acc.y * inv + bv.y;
  o.z = hv.z + acc.z * inv + bv.z;
  o.w = hv.w + acc.w * inv + bv.w;
  *(float4*)(h2 + (size_t)n * 256 + lane * 4) = o;
}

// ---------------------------------------------------------------------------
// weight prep: transpose + hi/lo bf16 split.  src [K][256] fp32 ->
// dhi/dlo [512][K] bf16 rows (colOff..colOff+255).
// ---------------------------------------------------------------------------
__global__ __launch_bounds__(256) void transpose_split(
    const float* __restrict__ src, int K,
    __hip_bfloat16* __restrict__ dhi, __hip_bfloat16* __restrict__ dlo, int colOff) {
  __shared__ float tile[32][33];
  int k0 = blockIdx.x * 32, j0 = blockIdx.y * 32;
  int tid = threadIdx.x;
  int r = tid >> 3, c4 = (tid & 7) * 4;
  float4 v = *(const float4*)(src + (size_t)(k0 + r) * 256 + j0 + c4);
  tile[r][c4] = v.x; tile[r][c4 + 1] = v.y; tile[r][c4 + 2] = v.z; tile[r][c4 + 3] = v.w;
  __syncthreads();
  int jr = tid >> 3, k4 = (tid & 7) * 4;
  unsigned short h[4], l[4];
#pragma unroll
  for (int i = 0; i < 4; ++i) {
    float f = tile[k4 + i][jr];
    __hip_bfloat16 hb = __float2bfloat16(f);
    float hf = __bfloat162float(hb);
    __hip_bfloat16 lb = __float2bfloat16(f - hf);
    h[i] = __builtin_bit_cast(unsigned short, hb);
    l[i] = __builtin_bit_cast(unsigned short, lb);
  }
  size_t idx = (size_t)(colOff + j0 + jr) * K + k0 + k4;
  ushort4 hv; hv.x = h[0]; hv.y = h[1]; hv.z = h[2]; hv.w = h[3];
  ushort4 lv; lv.x = l[0]; lv.y = l[1]; lv.z = l[2]; lv.w = l[3];
  *(ushort4*)((unsigned short*)dhi + idx) = hv;
  *(ushort4*)((unsigned short*)dlo + idx) = lv;
}

// ---------------------------------------------------------------------------
// split-bf16 MFMA GEMM:  C[M][512] = A[M][K](fp32) @ B[K][512]
// via 3-term bf16 emulation. BM=128 BN=128 BK=32, 4 waves (2x2),
// 16x16x32 bf16 MFMA. A reg-staged + split in kernel; B pre-split/transposed
// [512][K] bf16 hi/lo, staged with global_load_lds (swizzled source).
// LDS slot swizzle: slot' = slot ^ ((row>>1)&3)  (16B slots, 64B rows).
// ---------------------------------------------------------------------------
__global__ __launch_bounds__(256) void gemm_mfma3(
    const float* __restrict__ A, const __hip_bfloat16* __restrict__ BhiT,
    const __hip_bfloat16* __restrict__ BloT, float* __restrict__ C,
    int M, int K) {
  __shared__ __align__(16) unsigned short smem[16384];  // 32KB
  unsigned short* ahiS = smem;            // [128 rows][32 k] bf16
  unsigned short* aloS = smem + 4096;
  unsigned short* bhiS = smem + 8192;     // [128 cols][32 k] bf16
  unsigned short* bloS = smem + 12288;
  const int tid = threadIdx.x;
  const int lane = tid & 63, w = tid >> 6;
  const int wm = w >> 1, wn = w & 1;
  const int bm = blockIdx.y * 128, bn = blockIdx.x * 128;
  const unsigned short* BhiU = (const unsigned short*)BhiT;
  const unsigned short* BloU = (const unsigned short*)BloT;

  f32x4 zero = {0.f, 0.f, 0.f, 0.f};
  f32x4 acc[4][4];
#pragma unroll
  for (int m = 0; m < 4; ++m)
#pragma unroll
    for (int n = 0; n < 4; ++n) acc[m][n] = zero;

  for (int k0 = 0; k0 < K; k0 += 32) {
    __syncthreads();
    // ---- B staging: async global->LDS, source pre-swizzled ----
#pragma unroll
    for (int q = 0; q < 2; ++q) {
      int w2q = w * 2 + q;
      int lin = w2q * 64 + lane;
      int col = lin >> 2, s = lin & 3;
      int kk = k0 + ((s ^ ((col >> 1) & 3)) << 3);
      const unsigned short* gh = BhiU + (size_t)(bn + col) * K + kk;
      const unsigned short* gl = BloU + (size_t)(bn + col) * K + kk;
      __builtin_amdgcn_global_load_lds(
          (const __attribute__((address_space(1))) void*)gh,
          (__attribute__((address_space(3))) void*)(bhiS + w2q * 512), 16, 0, 0);
      __builtin_amdgcn_global_load_lds(
          (const __attribute__((address_space(1))) void*)gl,
          (__attribute__((address_space(3))) void*)(bloS + w2q * 512), 16, 0, 0);
    }
    // ---- A staging: fp32 -> hi/lo bf16, swizzled ds_write ----
#pragma unroll
    for (int b = 0; b < 2; ++b) {
      int slin = b * 256 + tid;
      int row = slin >> 2, s = slin & 3;
      const float* ap = A + (size_t)(bm + row) * K + k0 + s * 8;
      float4 v0 = *(const float4*)ap;
      float4 v1 = *(const float4*)(ap + 4);
      float fv[8] = {v0.x, v0.y, v0.z, v0.w, v1.x, v1.y, v1.z, v1.w};
      unsigned int hp[4], lp[4];
#pragma unroll
      for (int e = 0; e < 4; ++e) {
        __hip_bfloat16 h0 = __float2bfloat16(fv[2 * e]);
        __hip_bfloat16 h1 = __float2bfloat16(fv[2 * e + 1]);
        float r0 = fv[2 * e] - __bfloat162float(h0);
        float r1 = fv[2 * e + 1] - __bfloat162float(h1);
        __hip_bfloat16 l0 = __float2bfloat16(r0);
        __hip_bfloat16 l1 = __float2bfloat16(r1);
        hp[e] = (unsigned int)__builtin_bit_cast(unsigned short, h0) |
                ((unsigned int)__builtin_bit_cast(unsigned short, h1) << 16);
        lp[e] = (unsigned int)__builtin_bit_cast(unsigned short, l0) |
                ((unsigned int)__builtin_bit_cast(unsigned short, l1) << 16);
      }
      int off = row * 32 + ((s ^ ((row >> 1) & 3)) << 3);
      uint4 hv = make_uint4(hp[0], hp[1], hp[2], hp[3]);
      uint4 lv = make_uint4(lp[0], lp[1], lp[2], lp[3]);
      *(uint4*)(ahiS + off) = hv;
      *(uint4*)(aloS + off) = lv;
    }
    __syncthreads();
    // ---- compute ----
    const int ks = lane >> 4, fr = lane & 15;
    short8 ah[4], al[4], bh[4], bl[4];
#pragma unroll
    for (int m = 0; m < 4; ++m) {
      int row = wm * 64 + m * 16 + fr;
      int off = row * 32 + ((ks ^ ((row >> 1) & 3)) << 3);
      ah[m] = *(const short8*)(ahiS + off);
      al[m] = *(const short8*)(aloS + off);
    }
#pragma unroll
    for (int n = 0; n < 4; ++n) {
      int col = wn * 64 + n * 16 + fr;
      int off = col * 32 + ((ks ^ ((col >> 1) & 3)) << 3);
      bh[n] = *(const short8*)(bhiS + off);
      bl[n] = *(const short8*)(bloS + off);
    }
#pragma unroll
    for (int m = 0; m < 4; ++m)
#pragma unroll
      for (int n = 0; n < 4; ++n) {
        acc[m][n] = __builtin_amdgcn_mfma_f32_16x16x32_bf16(ah[m], bh[n], acc[m][n], 0, 0, 0);
        acc[m][n] = __builtin_amdgcn_mfma_f32_16x16x32_bf16(ah[m], bl[n], acc[m][n], 0, 0, 0);
        acc[m][n] = __builtin_amdgcn_mfma_f32_16x16x32_bf16(al[m], bh[n], acc[m][n], 0, 0, 0);
      }
  }
  // ---- epilogue: D layout col=lane&15, row=(lane>>4)*4+reg ----
#pragma unroll
  for (int m = 0; m < 4; ++m) {
    int rbase = bm + wm * 64 + m * 16 + (lane >> 4) * 4;
#pragma unroll
    for (int n = 0; n < 4; ++n) {
      int col = bn + wn * 64 + n * 16 + (lane & 15);
#pragma unroll
      for (int r = 0; r < 4; ++r) {
        int row = rbase + r;
        if (row < M) C[(size_t)row * 512 + col] = acc[m][n][r];
      }
    }
  }
}

// fp32 SIMT GEMM kept for the small MLP head (K=256, ncols=64)
__global__ __launch_bounds__(256) void gemm_dual(
    const float* __restrict__ A, const float* __restrict__ B0,
    const float* __restrict__ B1, float* __restrict__ C0,
    float* __restrict__ C1, int M, int K, int ncols) {
  __shared__ float Ast[16][128];
  __shared__ float Bs[16][64];
  const int tid = threadIdx.x;
  int cb = blockIdx.x;
  const int per = ncols >> 6;
  const float* B = B0;
  float* C = C0;
  if (cb >= per) { B = B1; C = C1; cb -= per; }
  const int bn = cb << 6;
  const int bm = blockIdx.y << 7;
  const int ty = tid >> 4, tx = tid & 15;
  float acc[8][4] = {};
  for (int k0 = 0; k0 < K; k0 += 16) {
#pragma unroll
    for (int i = 0; i < 2; ++i) {
      int idx = tid + i * 256;
      int r = idx >> 2, kq = (idx & 3) << 2;
      float4 v = make_float4(0.f, 0.f, 0.f, 0.f);
      int row = bm + r;
      if (row < M) v = *(const float4*)(A + (size_t)row * K + k0 + kq);
      Ast[kq + 0][r] = v.x; Ast[kq + 1][r] = v.y;
      Ast[kq + 2][r] = v.z; Ast[kq + 3][r] = v.w;
    }
    {
      int kb = tid >> 4, nq = (tid & 15) << 2;
      *(float4*)&Bs[kb][nq] = *(const float4*)(B + (size_t)(k0 + kb) * ncols + bn + nq);
    }
    __syncthreads();
#pragma unroll
    for (int kk = 0; kk < 16; ++kk) {
      float4 a0 = *(const float4*)&Ast[kk][ty * 8];
      float4 a1 = *(const float4*)&Ast[kk][ty * 8 + 4];
      float4 b = *(const float4*)&Bs[kk][tx * 4];
      float av[8] = {a0.x, a0.y, a0.z, a0.w, a1.x, a1.y, a1.z, a1.w};
      float bv[4] = {b.x, b.y, b.z, b.w};
#pragma unroll
      for (int i2 = 0; i2 < 8; ++i2)
#pragma unroll
        for (int j2 = 0; j2 < 4; ++j2) acc[i2][j2] += av[i2] * bv[j2];
    }
    __syncthreads();
  }
#pragma unroll
  for (int i2 = 0; i2 < 8; ++i2) {
    int row = bm + ty * 8 + i2;
    if (row < M) {
      float4 v = make_float4(acc[i2][0], acc[i2][1], acc[i2][2], acc[i2][3]);
      *(float4*)(C + (size_t)row * ncols + bn + tx * 4) = v;
    }
  }
}

__global__ __launch_bounds__(256) void mlp_out(
    const float* __restrict__ a, const float* __restrict__ w2,
    const float* __restrict__ b2, float* __restrict__ out) {
  __shared__ float ws[128];
  __shared__ float bs[2];
  int tid = threadIdx.x;
  if (tid < 128) ws[tid] = w2[tid];
  if (tid < 2) bs[tid] = b2[tid];
  __syncthreads();
  int n = blockIdx.x * 256 + tid;
  if (n >= NNODES) return;
  const float* ar = a + (size_t)n * 64;
  float a0 = bs[0], a1 = bs[1];
#pragma unroll 8
  for (int j = 0; j < 64; ++j) {
    float v = ar[j];
    a0 += v * ws[2 * j];
    a1 += v * ws[2 * j + 1];
  }
  out[2 * n] = a0;
  out[2 * n + 1] = a1;
}

// ---------------------------------------------------------------------------
extern "C" void kernel_launch(void* const* d_in, const int* in_sizes, int n_in,
                              void* d_out, int out_size, void* d_ws, size_t ws_size,
                              hipStream_t stream) {
  const float* x       = (const float*)d_in[0];
  const float* conv1_w = (const float*)d_in[1];
  const float* conv1_b = (const float*)d_in[2];
  const float* bn_c1_g = (const float*)d_in[3];
  const float* bn_c1_b = (const float*)d_in[4];
  const float* conv2_w = (const float*)d_in[5];
  const float* conv2_b = (const float*)d_in[6];
  const float* bn_c2_g = (const float*)d_in[7];
  const float* bn_c2_b = (const float*)d_in[8];
  const float* ws0     = (const float*)d_in[9];
  const float* wn0     = (const float*)d_in[10];
  const float* b0      = (const float*)d_in[11];
  const float* ws_rest = (const float*)d_in[12];
  const float* wn_rest = (const float*)d_in[13];
  const float* b_rest  = (const float*)d_in[14];
  const float* bn_g    = (const float*)d_in[15];
  const float* bn_b    = (const float*)d_in[16];
  const float* mlp_w1  = (const float*)d_in[17];
  const float* mlp_b1  = (const float*)d_in[18];
  const float* mlp_bn_g= (const float*)d_in[19];
  const float* mlp_bn_b= (const float*)d_in[20];
  const float* mlp_w2  = (const float*)d_in[21];
  const float* mlp_b2  = (const float*)d_in[22];
  const int*   edges   = (const int*)d_in[23];

  float* outp = (float*)d_out;
  float* cnn1 = outp + 20000;
  float* cnn2 = cnn1 + (size_t)NNODES * 8960;
  float* fin  = cnn2 + (size_t)NNODES * 8960;

  float* F     = (float*)d_ws;
  float* ssum  = F;                          // 256
  float* sssq  = F + 256;                    // 256
  float* scale = F + 512;                    // 256
  float* shift = F + 768;                    // 256
  float* denom = F + 1024;                   // 10000
  float* hsn   = F + 11024;                  // 10000*512
  float* h2    = hsn + (size_t)10000 * 512;  // 10000*256
  float* hbuf  = h2 + (size_t)10000 * 256;   // 10112*256 (padded rows readable)
  float* a64   = hbuf + (size_t)10112 * 256; // 10000*64
  __hip_bfloat16* b0hi = (__hip_bfloat16*)(a64 + (size_t)10000 * 64);  // 512*8960
  __hip_bfloat16* b0lo = b0hi + (size_t)512 * 8960;
  __hip_bfloat16* brhi = b0lo + (size_t)512 * 8960;   // 3 * 512*256
  __hip_bfloat16* brlo = brhi + (size_t)3 * 512 * 256;
  int* deg_i    = (int*)(brlo + (size_t)3 * 512 * 256);
  int* cursor   = deg_i + NNODES;
  int* rowstart = cursor + NNODES;           // N+1
  int* csr_src  = rowstart + NNODES + 1;     // E

  // ---- weight prep (transpose + hi/lo split) ----
  transpose_split<<<dim3(280, 8), 256, 0, stream>>>(ws0, 8960, b0hi, b0lo, 0);
  transpose_split<<<dim3(280, 8), 256, 0, stream>>>(wn0, 8960, b0hi, b0lo, 256);
  for (int l = 0; l < 3; ++l) {
    transpose_split<<<dim3(8, 8), 256, 0, stream>>>(
        ws_rest + (size_t)l * 65536, 256, brhi + (size_t)l * 131072,
        brlo + (size_t)l * 131072, 0);
    transpose_split<<<dim3(8, 8), 256, 0, stream>>>(
        wn_rest + (size_t)l * 65536, 256, brhi + (size_t)l * 131072,
        brlo + (size_t)l * 131072, 256);
  }

  // ---- CNN stage 1 ----
  hipMemsetAsync(ssum, 0, 512 * sizeof(float), stream);
  conv1_stats<<<512, 256, 0, stream>>>(x, conv1_w, conv1_b, cnn1, ssum, sssq);
  finalize_stats<<<1, 64, 0, stream>>>(ssum, sssq, bn_c1_g, bn_c1_b, scale, shift,
                                       1.f / 1400000.f, 64);
  bn_relu_chan<<<2048, 256, 0, stream>>>(cnn1, nullptr, scale, shift, 22400000);

  // ---- CNN stage 2 (+residual) ----
  hipMemsetAsync(ssum, 0, 512 * sizeof(float), stream);
  conv2_stats<<<1024, 256, 0, stream>>>(cnn1, conv2_w, conv2_b, cnn2, ssum, sssq);
  finalize_stats<<<1, 64, 0, stream>>>(ssum, sssq, bn_c2_g, bn_c2_b, scale, shift,
                                       1.f / 1400000.f, 64);
  bn_relu_chan<<<2048, 256, 0, stream>>>(cnn2, cnn1, scale, shift, 22400000);

  // ---- graph prep (CSR) ----
  hipMemsetAsync(deg_i, 0, 2 * NNODES * sizeof(int), stream);
  hist_deg<<<512, 256, 0, stream>>>(edges, deg_i);
  scan_deg<<<1, 1024, 0, stream>>>(deg_i, rowstart, denom);
  fill_csr<<<512, 256, 0, stream>>>(edges, rowstart, cursor, csr_src);

  // ---- 4 SAGE layers ----
  for (int l = 0; l < 4; ++l) {
    const float* A = (l == 0) ? cnn2 : hbuf;
    int K          = (l == 0) ? 8960 : 256;
    const __hip_bfloat16* Bh = (l == 0) ? b0hi : brhi + (size_t)(l - 1) * 131072;
    const __hip_bfloat16* Bl = (l == 0) ? b0lo : brlo + (size_t)(l - 1) * 131072;
    const float* bb = (l == 0) ? b0 : b_rest + (size_t)(l - 1) * 256;
    gemm_mfma3<<<dim3(4, 79), 256, 0, stream>>>(A, Bh, Bl, hsn, NNODES, K);
    combine_neigh<<<2500, 256, 0, stream>>>(hsn, rowstart, csr_src, denom, bb, h2);
    hipMemsetAsync(ssum, 0, 512 * sizeof(float), stream);
    col_stats<<<512, 256, 0, stream>>>(h2, NNODES, 256, ssum, sssq);
    finalize_stats<<<1, 256, 0, stream>>>(ssum, sssq, bn_g + l * 256, bn_b + l * 256,
                                          scale, shift, 1e-4f, 256);
    bn_relu_nodes<<<1024, 256, 0, stream>>>(h2, hbuf, scale, shift,
                                            (l == 3) ? fin : nullptr,
                                            (l > 0) ? 1 : 0, 640000, 63);
  }

  // ---- MLP head ----
  gemm_dual<<<dim3(1, 79), 256, 0, stream>>>(hbuf, mlp_w1, nullptr, a64, nullptr,
                                             NNODES, 256, 64);
  hipMemsetAsync(ssum, 0, 512 * sizeof(float), stream);
  col_stats<<<512, 256, 0, stream>>>(a64, NNODES, 64, ssum, sssq);
  finalize_stats<<<1, 64, 0, stream>>>(ssum, sssq, mlp_bn_g, mlp_bn_b, scale, shift,
                                       1e-4f, 64);
  bn_relu_nodes<<<512, 256, 0, stream>>>(a64, a64, scale, shift, nullptr, 0, 160000, 15);
  mlp_out<<<40, 256, 0, stream>>>(a64, mlp_w2, mlp_b2, outp);
}